// Round 3
// baseline (149.397 us; speedup 1.0000x reference)
//
#include <hip/hip_runtime.h>

// x [B=64, C=512, H=28, W=28] f32, cc [B,H,W] bool.
// out[b, 0:512]    = (sum_hw x*m + x[b,c,0,0]) / (cnt==0 ? 1 : cnt)
// out[b, 512:1024] = max_hw x
//
// Fused, barrier-free. Each wave owns 8 channels of one batch, streams x with
// coalesced float4 loads. ROUND-2 CHANGE: loads are REGULAR (not nontemporal)
// — the harness re-poison writes x through L2/L3 right before this kernel, so
// any L3-resident fraction of x should be read at Infinity-Cache BW instead
// of HBM; for the non-resident remainder regular loads cost nothing (read-
// once stream, no cache competition). Everything else identical to round 1:
// one-vote mask encoding detection, channel-splitting butterfly reduction
// (40 shuffles), single hoisted tail branch, 16 waves/CU.

#define HW 784      // 28*28
#define NC 512
#define NB 64

__device__ __forceinline__ float dot4(float4 a, float4 b) {
    return a.x * b.x + a.y * b.y + a.z * b.z + a.w * b.w;
}
__device__ __forceinline__ float max4(float4 a) {
    return fmaxf(fmaxf(a.x, a.y), fmaxf(a.z, a.w));
}
__device__ __forceinline__ float sum4(float4 a) {
    return a.x + a.y + a.z + a.w;
}
__device__ __forceinline__ float4 unpack_u8(unsigned int u) {
    return make_float4((float)(u & 0xffu), (float)((u >> 8) & 0xffu),
                       (float)((u >> 16) & 0xffu), (float)(u >> 24));
}
__device__ __forceinline__ float nz(int v) { return v ? 1.0f : 0.0f; }
__device__ __forceinline__ float4 unpack_nz(int4 v) {
    return make_float4(nz(v.x), nz(v.y), nz(v.z), nz(v.w));
}

__global__ __launch_bounds__(256, 4) void pool_fused_kernel(
    const float* __restrict__ x, const void* __restrict__ cc,
    float* __restrict__ out)
{
    const int blk  = blockIdx.x;      // 1024 blocks
    const int b    = blk >> 4;
    const int grp  = blk & 15;
    const int t    = threadIdx.x;
    const int wave = t >> 6;
    const int lane = t & 63;
    const int c0   = grp * 32 + wave * 8;   // 8 channels per wave

    // ---- mask row probe: 784 B at byte offset b*784 (in-bounds for every
    // encoding). If encoding IS u8, these dwords are the mask row itself.
    const unsigned int* row8 =
        (const unsigned int*)((const unsigned char*)cc + (size_t)b * HW);
    unsigned int r0 = row8[lane];
    unsigned int r1 = row8[lane + 64];
    unsigned int r2 = row8[lane + 128];
    unsigned int r3 = (lane < 4) ? row8[lane + 192] : 0u;

    // u8 iff any dword has a set byte above byte0 that isn't the f32-1.0
    // pattern. int32/f32 0-1 data only ever shows 0x0, 0x1, 0x3F800000.
    auto not4b = [](unsigned int v) {
        return (v & 0xFFFFFF00u) != 0u && v != 0x3F800000u;
    };
    const bool isU8 = __any(not4b(r0) || not4b(r1) || not4b(r2) || not4b(r3));

    // ---- mask row -> registers (lane covers float4s lane, +64, +128, +192<4)
    float4 m0, m1, m2, m3 = make_float4(0.f, 0.f, 0.f, 0.f);
    if (isU8) {
        m0 = unpack_u8(r0);
        m1 = unpack_u8(r1);
        m2 = unpack_u8(r2);
        if (lane < 4) m3 = unpack_u8(r3);
    } else {
        // 4-byte encoding (int32 or f32): nonzero bits == mask 1
        const int4* mi = (const int4*)cc + (size_t)b * 196;
        m0 = unpack_nz(mi[lane]);
        m1 = unpack_nz(mi[lane + 64]);
        m2 = unpack_nz(mi[lane + 128]);
        if (lane < 4) m3 = unpack_nz(mi[lane + 192]);
    }

    float mc = sum4(m0) + sum4(m1) + sum4(m2) + sum4(m3);  // partial count

    // ---- 8 channels per wave: coalesced float4 stream of x ----
    const float4* xr = (const float4*)(x + (size_t)(b * NC + c0) * HW);
    float s[8], mx[8];
#pragma unroll
    for (int j = 0; j < 8; ++j) {
        const float4* xj = xr + j * 196;
        float4 q0 = xj[lane];
        float4 q1 = xj[lane + 64];
        float4 q2 = xj[lane + 128];
        float sum = dot4(q0, m0) + dot4(q1, m1) + dot4(q2, m2);
        float mm  = fmaxf(fmaxf(max4(q0), max4(q1)), max4(q2));
        if (lane == 0) sum += q0.x;   // reference's + x[b,c,0,0] term
        s[j] = sum; mx[j] = mm;
    }
    if (lane < 4) {                    // single hoisted tail branch
#pragma unroll
        for (int j = 0; j < 8; ++j) {
            float4 q3 = xr[j * 196 + 192 + lane];
            s[j] += dot4(q3, m3);
            mx[j] = fmaxf(mx[j], max4(q3));
        }
    }

    // ---- mask count: full butterfly, every lane ends with the total ----
#pragma unroll
    for (int off = 32; off; off >>= 1) mc += __shfl_xor(mc, off);

    // ---- channel-splitting butterfly: 8 -> 4 -> 2 -> 1 values/lane ----
    // After each xor level, the half-wave adopts the upper channels.
    // Net mapping: lane group 8g ends up holding channel c0+g.
    const bool h5 = (lane & 32) != 0;
    float s4[4], y4[4];
#pragma unroll
    for (int k = 0; k < 4; ++k) {
        float sa = s[k]     + __shfl_xor(s[k],     32);
        float sb = s[k + 4] + __shfl_xor(s[k + 4], 32);
        s4[k] = h5 ? sb : sa;
        float ya = fmaxf(mx[k],     __shfl_xor(mx[k],     32));
        float yb = fmaxf(mx[k + 4], __shfl_xor(mx[k + 4], 32));
        y4[k] = h5 ? yb : ya;
    }
    const bool h4 = (lane & 16) != 0;
    float s2[2], y2[2];
#pragma unroll
    for (int k = 0; k < 2; ++k) {
        float sa = s4[k]     + __shfl_xor(s4[k],     16);
        float sb = s4[k + 2] + __shfl_xor(s4[k + 2], 16);
        s2[k] = h4 ? sb : sa;
        float ya = fmaxf(y4[k],     __shfl_xor(y4[k],     16));
        float yb = fmaxf(y4[k + 2], __shfl_xor(y4[k + 2], 16));
        y2[k] = h4 ? yb : ya;
    }
    const bool h3 = (lane & 8) != 0;
    float s1, y1;
    {
        float sa = s2[0] + __shfl_xor(s2[0], 8);
        float sb = s2[1] + __shfl_xor(s2[1], 8);
        s1 = h3 ? sb : sa;
        float ya = fmaxf(y2[0], __shfl_xor(y2[0], 8));
        float yb = fmaxf(y2[1], __shfl_xor(y2[1], 8));
        y1 = h3 ? yb : ya;
    }
#pragma unroll
    for (int off = 4; off; off >>= 1) {
        s1 += __shfl_xor(s1, off);
        y1 = fmaxf(y1, __shfl_xor(y1, off));
    }

    if ((lane & 7) == 0) {
        const int g = lane >> 3;                 // this group's channel
        const float inv = 1.0f / ((mc == 0.0f) ? 1.0f : mc);
        const int c = c0 + g;
        out[(size_t)b * (2 * NC) + c]      = s1 * inv;
        out[(size_t)b * (2 * NC) + NC + c] = y1;
    }
}

extern "C" void kernel_launch(void* const* d_in, const int* in_sizes, int n_in,
                              void* d_out, int out_size, void* d_ws, size_t ws_size,
                              hipStream_t stream) {
    const float* x  = (const float*)d_in[0];
    const void*  cc = d_in[1];
    float* out = (float*)d_out;
    pool_fused_kernel<<<dim3(NB * 16), dim3(256), 0, stream>>>(x, cc, out);
}

// Round 4
// 141.954 us; speedup vs baseline: 1.0524x; 1.0524x over previous
//
#include <hip/hip_runtime.h>

// x [B=64, C=512, H=28, W=28] f32, cc [B,H,W] bool.
// out[b, 0:512]    = (sum_hw x*m + x[b,c,0,0]) / (cnt==0 ? 1 : cnt)
// out[b, 512:1024] = max_hw x
//
// Fused, barrier-free. Each wave owns 8 channels of one batch, streams x with
// NONTEMPORAL float4 loads — measured: nt vs regular loads = 142.3 vs 149.4 µs
// (regular loads allocate the 103 MB read-once stream in L2/L3; eviction
// traffic costs ~7 µs — round-3 experiment). Mask encoding handled with ONE
// wave vote: u8 vs 4-byte (int32 0/1 and f32 0/1.0f collapse to the same
// "bits != 0" rule). Reduction is a channel-splitting butterfly (40 shuffles,
// fully hidden under the memory stream — round-2 experiment). 1024 blocks =
// 4 blocks/CU, 16 waves/CU (VGPR capped <=128).

#define HW 784      // 28*28
#define NC 512
#define NB 64

typedef float  vfloat4 __attribute__((ext_vector_type(4)));

__device__ __forceinline__ float dot4(float4 a, float4 b) {
    return a.x * b.x + a.y * b.y + a.z * b.z + a.w * b.w;
}
__device__ __forceinline__ float max4(float4 a) {
    return fmaxf(fmaxf(a.x, a.y), fmaxf(a.z, a.w));
}
__device__ __forceinline__ float sum4(float4 a) {
    return a.x + a.y + a.z + a.w;
}
__device__ __forceinline__ float4 unpack_u8(unsigned int u) {
    return make_float4((float)(u & 0xffu), (float)((u >> 8) & 0xffu),
                       (float)((u >> 16) & 0xffu), (float)(u >> 24));
}
__device__ __forceinline__ float nz(int v) { return v ? 1.0f : 0.0f; }
__device__ __forceinline__ float4 unpack_nz(int4 v) {
    return make_float4(nz(v.x), nz(v.y), nz(v.z), nz(v.w));
}
__device__ __forceinline__ float4 ntload4(const float4* p) {
    vfloat4 v = __builtin_nontemporal_load((const vfloat4*)p);
    return make_float4(v.x, v.y, v.z, v.w);
}

__global__ __launch_bounds__(256, 4) void pool_fused_kernel(
    const float* __restrict__ x, const void* __restrict__ cc,
    float* __restrict__ out)
{
    const int blk  = blockIdx.x;      // 1024 blocks
    const int b    = blk >> 4;
    const int grp  = blk & 15;
    const int t    = threadIdx.x;
    const int wave = t >> 6;
    const int lane = t & 63;
    const int c0   = grp * 32 + wave * 8;   // 8 channels per wave

    // ---- mask row probe: 784 B at byte offset b*784 (in-bounds for every
    // encoding). If encoding IS u8, these dwords are the mask row itself.
    const unsigned int* row8 =
        (const unsigned int*)((const unsigned char*)cc + (size_t)b * HW);
    unsigned int r0 = row8[lane];
    unsigned int r1 = row8[lane + 64];
    unsigned int r2 = row8[lane + 128];
    unsigned int r3 = (lane < 4) ? row8[lane + 192] : 0u;

    // u8 iff any dword has a set byte above byte0 that isn't the f32-1.0
    // pattern. int32/f32 0-1 data only ever shows 0x0, 0x1, 0x3F800000.
    auto not4b = [](unsigned int v) {
        return (v & 0xFFFFFF00u) != 0u && v != 0x3F800000u;
    };
    const bool isU8 = __any(not4b(r0) || not4b(r1) || not4b(r2) || not4b(r3));

    // ---- mask row -> registers (lane covers float4s lane, +64, +128, +192<4)
    float4 m0, m1, m2, m3 = make_float4(0.f, 0.f, 0.f, 0.f);
    if (isU8) {
        m0 = unpack_u8(r0);
        m1 = unpack_u8(r1);
        m2 = unpack_u8(r2);
        if (lane < 4) m3 = unpack_u8(r3);
    } else {
        // 4-byte encoding (int32 or f32): nonzero bits == mask 1
        const int4* mi = (const int4*)cc + (size_t)b * 196;
        m0 = unpack_nz(mi[lane]);
        m1 = unpack_nz(mi[lane + 64]);
        m2 = unpack_nz(mi[lane + 128]);
        if (lane < 4) m3 = unpack_nz(mi[lane + 192]);
    }

    float mc = sum4(m0) + sum4(m1) + sum4(m2) + sum4(m3);  // partial count

    // ---- 8 channels per wave: coalesced nontemporal float4 stream of x ----
    const float4* xr = (const float4*)(x + (size_t)(b * NC + c0) * HW);
    float s[8], mx[8];
#pragma unroll
    for (int j = 0; j < 8; ++j) {
        const float4* xj = xr + j * 196;
        float4 q0 = ntload4(xj + lane);
        float4 q1 = ntload4(xj + lane + 64);
        float4 q2 = ntload4(xj + lane + 128);
        float sum = dot4(q0, m0) + dot4(q1, m1) + dot4(q2, m2);
        float mm  = fmaxf(fmaxf(max4(q0), max4(q1)), max4(q2));
        if (lane == 0) sum += q0.x;   // reference's + x[b,c,0,0] term
        s[j] = sum; mx[j] = mm;
    }
    if (lane < 4) {                    // single hoisted tail branch
#pragma unroll
        for (int j = 0; j < 8; ++j) {
            float4 q3 = ntload4(xr + j * 196 + 192 + lane);
            s[j] += dot4(q3, m3);
            mx[j] = fmaxf(mx[j], max4(q3));
        }
    }

    // ---- mask count: full butterfly, every lane ends with the total ----
#pragma unroll
    for (int off = 32; off; off >>= 1) mc += __shfl_xor(mc, off);

    // ---- channel-splitting butterfly: 8 -> 4 -> 2 -> 1 values/lane ----
    // After each xor level, the half-wave adopts the upper channels.
    // Net mapping: lane group 8g ends up holding channel c0+g.
    const bool h5 = (lane & 32) != 0;
    float s4[4], y4[4];
#pragma unroll
    for (int k = 0; k < 4; ++k) {
        float sa = s[k]     + __shfl_xor(s[k],     32);
        float sb = s[k + 4] + __shfl_xor(s[k + 4], 32);
        s4[k] = h5 ? sb : sa;
        float ya = fmaxf(mx[k],     __shfl_xor(mx[k],     32));
        float yb = fmaxf(mx[k + 4], __shfl_xor(mx[k + 4], 32));
        y4[k] = h5 ? yb : ya;
    }
    const bool h4 = (lane & 16) != 0;
    float s2[2], y2[2];
#pragma unroll
    for (int k = 0; k < 2; ++k) {
        float sa = s4[k]     + __shfl_xor(s4[k],     16);
        float sb = s4[k + 2] + __shfl_xor(s4[k + 2], 16);
        s2[k] = h4 ? sb : sa;
        float ya = fmaxf(y4[k],     __shfl_xor(y4[k],     16));
        float yb = fmaxf(y4[k + 2], __shfl_xor(y4[k + 2], 16));
        y2[k] = h4 ? yb : ya;
    }
    const bool h3 = (lane & 8) != 0;
    float s1, y1;
    {
        float sa = s2[0] + __shfl_xor(s2[0], 8);
        float sb = s2[1] + __shfl_xor(s2[1], 8);
        s1 = h3 ? sb : sa;
        float ya = fmaxf(y2[0], __shfl_xor(y2[0], 8));
        float yb = fmaxf(y2[1], __shfl_xor(y2[1], 8));
        y1 = h3 ? yb : ya;
    }
#pragma unroll
    for (int off = 4; off; off >>= 1) {
        s1 += __shfl_xor(s1, off);
        y1 = fmaxf(y1, __shfl_xor(y1, off));
    }

    if ((lane & 7) == 0) {
        const int g = lane >> 3;                 // this group's channel
        const float inv = 1.0f / ((mc == 0.0f) ? 1.0f : mc);
        const int c = c0 + g;
        out[(size_t)b * (2 * NC) + c]      = s1 * inv;
        out[(size_t)b * (2 * NC) + NC + c] = y1;
    }
}

extern "C" void kernel_launch(void* const* d_in, const int* in_sizes, int n_in,
                              void* d_out, int out_size, void* d_ws, size_t ws_size,
                              hipStream_t stream) {
    const float* x  = (const float*)d_in[0];
    const void*  cc = d_in[1];
    float* out = (float*)d_out;
    pool_fused_kernel<<<dim3(NB * 16), dim3(256), 0, stream>>>(x, cc, out);
}